// Round 4
// baseline (584.296 us; speedup 1.0000x reference)
//
#include <hip/hip_runtime.h>
#include <hip/hip_bf16.h>
#include <stdint.h>

// Problem constants
#define H2      1024
#define SEQ     512
#define BATCH   64
#define M_TOTAL (SEQ * BATCH)   // 32768 rows, row m = s*64 + b (enc layout (S,B,H2))

typedef __attribute__((ext_vector_type(8))) short short8;  // 8 bf16 (4 VGPRs)
typedef __attribute__((ext_vector_type(4))) float f32x4;   // mfma acc

__device__ __forceinline__ unsigned pack2_bf16(float lo, float hi) {
    union { __hip_bfloat162 h; unsigned u; } v;
    v.h = __float22bfloat162_rn(make_float2(lo, hi));
    return v.u;
}

__device__ __forceinline__ float fast_tanh(float x) {
    float e = __expf(2.0f * x);
    return __fdividef(e - 1.0f, e + 1.0f);
}

// Swizzled W1e layout (MFMA-fragment-major), bf16:
//   region gr = RB*32 + KC  (RB = h>>4, KC = k>>5), 512 shorts each.
//   chunk L in [0,64): 8 shorts = (h = RB*16 + (L&15), k = KC*32 + (L>>4)*8).

// ------------------------------------------------------------------
// k_setup:
//   [0,512)   : W1 enc-slice -> bf16 W1e swizzled
//   [512,640) : zero logits (32768)
//   [640,704) : state projection sp[b][h] = sum_k st*W1 + b1 (both layers)
__global__ __launch_bounds__(256) void k_setup(const float* __restrict__ W1,
                                               const float* __restrict__ b1,
                                               const float* __restrict__ state,
                                               unsigned short* __restrict__ W1e,
                                               float* __restrict__ logits,
                                               float* __restrict__ sp) {
    int blk = blockIdx.x, tid = threadIdx.x;
    int lane = tid & 63;
    if (blk < 512) {
        // ---- W1e prep: 4 regions per block (wave w -> region blk*4+w) ----
        int gr = blk * 4 + (tid >> 6);
        int L  = ((lane & 3) << 4) | (lane >> 2);   // read-coalescing perm
        int h  = ((gr >> 5) << 4) + (L & 15);
        int k  = ((gr & 31) << 5) + ((L >> 4) << 3);
        const float* src = W1 + (size_t)h * 3072 + 2048 + k;
        float4 v0 = *(const float4*)(src);
        float4 v1 = *(const float4*)(src + 4);
        uint4 o;
        o.x = pack2_bf16(v0.x, v0.y); o.y = pack2_bf16(v0.z, v0.w);
        o.z = pack2_bf16(v1.x, v1.y); o.w = pack2_bf16(v1.z, v1.w);
        *(uint4*)(W1e + (size_t)gr * 512 + L * 8) = o;
    } else if (blk < 640) {
        logits[(blk - 512) * 256 + tid] = 0.f;
    } else {
        // ---- state projection: mT = blk-640 (16 h-rows), all 64 b, K=2048 ----
        int mT   = blk - 640;
        int wave = tid >> 6;                // b-tile 0..3
        int c    = lane & 15;
        int kq   = (lane >> 4) << 3;
        int h    = mT * 16 + c;
        int b    = wave * 16 + c;
        const float* ap = W1 + (size_t)h * 3072 + kq;   // state cols [0,2048)
        f32x4 acc = {0.f, 0.f, 0.f, 0.f};
        #pragma unroll 4
        for (int k0 = 0; k0 < 2048; k0 += 32) {
            int k = k0 + kq;
            float4 a0 = *(const float4*)(ap + k0);
            float4 a1 = *(const float4*)(ap + k0 + 4);
            int l = k >> 10, j = k & 1023;
            const float* bp = state + (((size_t)l * 64 + b) << 10) + j;
            float4 b0 = *(const float4*)bp;
            float4 b1v = *(const float4*)(bp + 4);
            union { short8 s; uint4 u; } fa, fb;
            fa.u.x = pack2_bf16(a0.x, a0.y); fa.u.y = pack2_bf16(a0.z, a0.w);
            fa.u.z = pack2_bf16(a1.x, a1.y); fa.u.w = pack2_bf16(a1.z, a1.w);
            fb.u.x = pack2_bf16(b0.x, b0.y); fb.u.y = pack2_bf16(b0.z, b0.w);
            fb.u.z = pack2_bf16(b1v.x, b1v.y); fb.u.w = pack2_bf16(b1v.z, b1v.w);
            acc = __builtin_amdgcn_mfma_f32_16x16x32_bf16(fa.s, fb.s, acc, 0, 0, 0);
        }
        int quad = lane >> 4;
        int bcol = wave * 16 + c;
        #pragma unroll
        for (int i = 0; i < 4; ++i) {
            int hh = mT * 16 + quad * 4 + i;
            sp[((size_t)bcol << 10) + hh] = acc[i] + b1[hh];
        }
    }
}

// ------------------------------------------------------------------
// k_energy: C(32768,1024) = enc(bf16-cast) @ W1e^T, fused tanh/W2/reduce.
// LDS-FREE: fragments load straight global->VGPR (operands are L2-resident:
// W1e 2MB/XCD-L2; enc panel 512KB shared by same-XCD n-tile siblings via the
// XCD swizzle). No __syncthreads in the K-loop -> no vmcnt(0) drain stalls;
// 1-deep register prefetch (load frags t+1, MFMA t) + free-running waves.
#define BM 128
#define BN 128
#define NT 32                   // K-steps of 32

__global__ __launch_bounds__(256, 2) void k_energy(const float* __restrict__ enc,
                                                   const unsigned short* __restrict__ W1e,
                                                   const float* __restrict__ sp,
                                                   const float* __restrict__ W2,
                                                   float* __restrict__ logits) {
    int bid = blockIdx.x;
    int c8  = bid & 7;                // XCD id (round-robin dispatch)
    int jj  = bid >> 3;
    int mT  = c8 * 32 + (jj >> 3);    // same-mT blocks share c8 -> same XCD L2
    int nT  = jj & 7;
    int n0  = nT * BN;
    int m0  = mT * BM;
    int tid  = threadIdx.x;
    int lane = tid & 63, wave = tid >> 6;
    int wm   = (wave >> 1) << 6;
    int wn   = (wave & 1) << 6;

    // A fragment i (m-subtile): lane reads enc row m0+wm+i*16+(lane&15),
    // 8 consecutive k at (lane>>4)*8 (+t*32) -> 32B/lane via 2 float4 loads.
    const float* pA[4];
    #pragma unroll
    for (int i = 0; i < 4; ++i)
        pA[i] = enc + (size_t)(m0 + wm + i * 16 + (lane & 15)) * 1024 + ((lane >> 4) << 3);
    // B fragment i (n-subtile): swizzled region nT*8 + (wn>>4) + i,
    // at KC=t offset t*512 + lane*8 -> lane-contiguous 1KB per fragment.
    const unsigned short* pB[4];
    #pragma unroll
    for (int i = 0; i < 4; ++i)
        pB[i] = W1e + (size_t)(nT * 8 + (wn >> 4) + i) * 16384 + lane * 8;

    f32x4 acc[4][4];
    #pragma unroll
    for (int mi = 0; mi < 4; ++mi)
        #pragma unroll
        for (int ni = 0; ni < 4; ++ni)
            acc[mi][ni] = (f32x4){0.f, 0.f, 0.f, 0.f};

    // ---- register pipeline: stage 0 ----
    float4 aC0[4], aC1[4];
    uint4  bC[4];
    #pragma unroll
    for (int i = 0; i < 4; ++i) {
        aC0[i] = *(const float4*)(pA[i]);
        aC1[i] = *(const float4*)(pA[i] + 4);
        bC[i]  = *(const uint4*)(pB[i]);
    }

    #pragma unroll 4
    for (int t = 0; t < NT; ++t) {
        float4 aN0[4], aN1[4];
        uint4  bN[4];
        if (t + 1 < NT) {
            int ao = (t + 1) * 32;             // enc k-advance (floats)
            int bo = (t + 1) * 512;            // W1e region advance (shorts)
            #pragma unroll
            for (int i = 0; i < 4; ++i) {
                aN0[i] = *(const float4*)(pA[i] + ao);
                aN1[i] = *(const float4*)(pA[i] + ao + 4);
                bN[i]  = *(const uint4*)(pB[i] + bo);
            }
        }

        short8 af[4], bf[4];
        #pragma unroll
        for (int i = 0; i < 4; ++i) {
            union { short8 s; uint4 u; } fa, fb;
            fa.u.x = pack2_bf16(aC0[i].x, aC0[i].y);
            fa.u.y = pack2_bf16(aC0[i].z, aC0[i].w);
            fa.u.z = pack2_bf16(aC1[i].x, aC1[i].y);
            fa.u.w = pack2_bf16(aC1[i].z, aC1[i].w);
            af[i] = fa.s;
            fb.u  = bC[i];
            bf[i] = fb.s;
        }
        #pragma unroll
        for (int mi = 0; mi < 4; ++mi)
            #pragma unroll
            for (int ni = 0; ni < 4; ++ni)
                acc[mi][ni] = __builtin_amdgcn_mfma_f32_16x16x32_bf16(af[mi], bf[ni], acc[mi][ni], 0, 0, 0);

        if (t + 1 < NT) {
            #pragma unroll
            for (int i = 0; i < 4; ++i) {
                aC0[i] = aN0[i]; aC1[i] = aN1[i]; bC[i] = bN[i];
            }
        }
    }

    // Epilogue: tanh + W2 dot, quad-shuffle reduce, atomic into logits[b][s]
    int c    = lane & 15;
    int quad = lane >> 4;
    float w2v[4];
    int   hcol[4];
    #pragma unroll
    for (int ni = 0; ni < 4; ++ni) {
        hcol[ni] = n0 + wn + ni * 16 + c;
        w2v[ni]  = W2[hcol[ni]];
    }
    #pragma unroll
    for (int mi = 0; mi < 4; ++mi) {
        #pragma unroll
        for (int i = 0; i < 4; ++i) {
            int m = m0 + wm + mi * 16 + quad * 4 + i;
            int b = m & 63;
            const float* sprow = sp + ((size_t)b << 10);
            float t = 0.f;
            #pragma unroll
            for (int ni = 0; ni < 4; ++ni) {
                float e = acc[mi][ni][i] + sprow[hcol[ni]];
                t = fmaf(fast_tanh(e), w2v[ni], t);
            }
            t += __shfl_xor(t, 1);
            t += __shfl_xor(t, 2);
            t += __shfl_xor(t, 4);
            t += __shfl_xor(t, 8);
            if (c == 0) atomicAdd(logits + (size_t)b * 512 + (m >> 6), t);
        }
    }
}

// ------------------------------------------------------------------
// k_softmax: softmax over s per b.
__global__ __launch_bounds__(256) void k_softmax(const float* __restrict__ logits,
                                                 float* __restrict__ alpha) {
    int b = blockIdx.x;
    int tid = threadIdx.x;
    int lane = tid & 63, wave = tid >> 6;
    float v0 = logits[(size_t)b * 512 + tid];
    float v1 = logits[(size_t)b * 512 + 256 + tid];
    float mx = fmaxf(v0, v1);
    #pragma unroll
    for (int o = 32; o; o >>= 1) mx = fmaxf(mx, __shfl_xor(mx, o));
    __shared__ float redm[4];
    if (lane == 0) redm[wave] = mx;
    __syncthreads();
    mx = fmaxf(fmaxf(redm[0], redm[1]), fmaxf(redm[2], redm[3]));
    float e0 = __expf(v0 - mx), e1 = __expf(v1 - mx);
    float s = e0 + e1;
    #pragma unroll
    for (int o = 32; o; o >>= 1) s += __shfl_xor(s, o);
    __shared__ float reds[4];
    if (lane == 0) reds[wave] = s;
    __syncthreads();
    s = reds[0] + reds[1] + reds[2] + reds[3];
    float inv = 1.0f / s;
    alpha[(size_t)b * 512 + tid]       = e0 * inv;
    alpha[(size_t)b * 512 + 256 + tid] = e1 * inv;
}

// ------------------------------------------------------------------
// k_context: partial ctx over s-chunks, no atomics.
//   grid 1024 = 16 s-chunks x 64 b; part[sc][b][h] in workspace (4 MB).
#define NSC 16
__global__ __launch_bounds__(256) void k_context(const float* __restrict__ enc,
                                                 const float* __restrict__ alpha,
                                                 float* __restrict__ part) {
    int b  = blockIdx.x & 63;
    int sc = blockIdx.x >> 6;            // 0..15
    int h  = threadIdx.x << 2;
    float4 acc = make_float4(0.f, 0.f, 0.f, 0.f);
    int sbase = sc * 32;
    #pragma unroll 4
    for (int si = 0; si < 32; ++si) {
        int s = sbase + si;
        float a = alpha[(size_t)b * 512 + s];
        float4 e = *(const float4*)(enc + (((size_t)s * 64 + b) << 10) + h);
        acc.x = fmaf(a, e.x, acc.x);
        acc.y = fmaf(a, e.y, acc.y);
        acc.z = fmaf(a, e.z, acc.z);
        acc.w = fmaf(a, e.w, acc.w);
    }
    *(float4*)(part + (((size_t)sc * 64 + b) << 10) + h) = acc;
}

// k_reduce: ctx[b][h] = sum_sc part[sc][b][h].  64 blocks x 256 thr x float4.
__global__ __launch_bounds__(256) void k_reduce(const float* __restrict__ part,
                                                float* __restrict__ ctx) {
    int b = blockIdx.x;
    int h = threadIdx.x << 2;
    float4 acc = make_float4(0.f, 0.f, 0.f, 0.f);
    #pragma unroll
    for (int sc = 0; sc < NSC; ++sc) {
        float4 p = *(const float4*)(part + (((size_t)sc * 64 + b) << 10) + h);
        acc.x += p.x; acc.y += p.y; acc.z += p.z; acc.w += p.w;
    }
    *(float4*)(ctx + ((size_t)b << 10) + h) = acc;
}

// ------------------------------------------------------------------
extern "C" void kernel_launch(void* const* d_in, const int* in_sizes, int n_in,
                              void* d_out, int out_size, void* d_ws, size_t ws_size,
                              hipStream_t stream) {
    const float* state = (const float*)d_in[0];   // (2, 64, 1024)
    const float* enc   = (const float*)d_in[1];   // (512, 64, 1024)
    const float* W1    = (const float*)d_in[2];   // (1024, 3072)
    const float* b1    = (const float*)d_in[3];   // (1024,)
    const float* W2    = (const float*)d_in[4];   // (1, 1024)
    // d_in[5] = b2: dropped — softmax is shift-invariant.

    float* ctx   = (float*)d_out;                 // (1,64,1024) = 65536 fp32
    float* alpha = (float*)d_out + 65536;         // (64,1,512)  = 32768 fp32

    char* ws = (char*)d_ws;
    unsigned short* W1e    = (unsigned short*)(ws);             // 2 MB bf16 swizzled
    float*          sp     = (float*)(ws + 2097152);            // 256 KB [b][h]
    float*          logits = (float*)(ws + 2097152 + 262144);   // 128 KB [b][s]
    float*          part   = (float*)(ws + 2097152 + 262144 + 131072); // 4 MB

    k_setup<<<704, 256, 0, stream>>>(W1, b1, state, W1e, logits, sp);
    k_energy<<<M_TOTAL / BM * (H2 / BN), 256, 0, stream>>>(enc, W1e, sp, W2, logits);
    k_softmax<<<64, 256, 0, stream>>>(logits, alpha);
    k_context<<<NSC * 64, 256, 0, stream>>>(enc, alpha, part);
    k_reduce<<<64, 256, 0, stream>>>(part, ctx);
}

// Round 5
// 381.060 us; speedup vs baseline: 1.5333x; 1.5333x over previous
//
#include <hip/hip_runtime.h>
#include <hip/hip_bf16.h>
#include <stdint.h>

// Problem constants
#define H2      1024
#define SEQ     512
#define BATCH   64
#define M_TOTAL (SEQ * BATCH)   // 32768 rows, row m = s*64 + b (enc layout (S,B,H2))

typedef __attribute__((ext_vector_type(8))) short short8;  // 8 bf16 (4 VGPRs)
typedef __attribute__((ext_vector_type(4))) float f32x4;   // mfma acc

__device__ __forceinline__ unsigned pack2_bf16(float lo, float hi) {
    union { __hip_bfloat162 h; unsigned u; } v;
    v.h = __float22bfloat162_rn(make_float2(lo, hi));
    return v.u;
}

__device__ __forceinline__ float fast_tanh(float x) {
    float e = __expf(2.0f * x);
    return __fdividef(e - 1.0f, e + 1.0f);
}

// Async global->LDS, 16B per lane; LDS dest = wave-uniform base + lane*16B.
__device__ __forceinline__ void gl_lds16(const unsigned short* g, unsigned short* l) {
    __builtin_amdgcn_global_load_lds(
        (const __attribute__((address_space(1))) unsigned int*)g,
        (__attribute__((address_space(3))) unsigned int*)l, 16, 0, 0);
}

// Swizzled operand layout (MFMA-fragment-major), bf16:
//   region gr = RB*32 + KC  (RB = row>>4, KC = k>>5), 512 shorts each.
//   chunk L in [0,64): 8 shorts = (row = RB*16 + (L&15), k = KC*32 + (L>>4)*8).
// Conversion kernels use L = lane: the 64 chunk-writes of a wave form ONE
// contiguous 1KB burst (lane-adjacent => store-coalesced). Reads cover
// 16 full cache lines per instr (rows RB*16..+15, 64B each) - no overfetch.

// ------------------------------------------------------------------
// k_setup: fused prep. Block ranges:
//   [0,512)      : W1 enc-slice -> bf16 W1e swizzled
//   [512,640)    : zero logits (32768)
//   [640,704)    : state projection sp[b][h] = sum_k st*W1 + b1 (both layers)
//   [704,2752)   : enc fp32 -> bf16 swizzled encb, 8 regions per wave (ILP)
#define CONV_BLKS 2048
#define CONV_STRIDE (CONV_BLKS * 256)     // threads in conv range
__global__ __launch_bounds__(256) void k_setup(const float* __restrict__ W1,
                                               const float* __restrict__ b1,
                                               const float* __restrict__ state,
                                               const float* __restrict__ enc,
                                               unsigned short* __restrict__ W1e,
                                               unsigned short* __restrict__ encb,
                                               float* __restrict__ logits,
                                               float* __restrict__ sp) {
    int blk = blockIdx.x, tid = threadIdx.x;
    int lane = tid & 63;
    if (blk < 512) {
        // ---- W1e prep: wave w -> region blk*4+w, chunk L = lane ----
        int gr = blk * 4 + (tid >> 6);
        int h  = ((gr >> 5) << 4) + (lane & 15);
        int k  = ((gr & 31) << 5) + ((lane >> 4) << 3);
        const float* src = W1 + (size_t)h * 3072 + 2048 + k;
        float4 v0 = *(const float4*)(src);
        float4 v1 = *(const float4*)(src + 4);
        uint4 o;
        o.x = pack2_bf16(v0.x, v0.y); o.y = pack2_bf16(v0.z, v0.w);
        o.z = pack2_bf16(v1.x, v1.y); o.w = pack2_bf16(v1.z, v1.w);
        *(uint4*)(W1e + (size_t)gr * 512 + lane * 8) = o;   // 1KB burst per wave
    } else if (blk < 640) {
        logits[(blk - 512) * 256 + tid] = 0.f;
    } else if (blk < 704) {
        // ---- state projection: mT = blk-640 (16 h-rows), all 64 b, K=2048 ----
        int mT   = blk - 640;
        int wave = tid >> 6;                // b-tile 0..3
        int c    = lane & 15;
        int kq   = (lane >> 4) << 3;
        int h    = mT * 16 + c;
        int b    = wave * 16 + c;
        const float* ap = W1 + (size_t)h * 3072 + kq;   // state cols [0,2048)
        f32x4 acc = {0.f, 0.f, 0.f, 0.f};
        #pragma unroll 4
        for (int k0 = 0; k0 < 2048; k0 += 32) {
            int k = k0 + kq;
            float4 a0 = *(const float4*)(ap + k0);
            float4 a1 = *(const float4*)(ap + k0 + 4);
            int l = k >> 10, j = k & 1023;
            const float* bp = state + (((size_t)l * 64 + b) << 10) + j;
            float4 b0 = *(const float4*)bp;
            float4 b1v = *(const float4*)(bp + 4);
            union { short8 s; uint4 u; } fa, fb;
            fa.u.x = pack2_bf16(a0.x, a0.y); fa.u.y = pack2_bf16(a0.z, a0.w);
            fa.u.z = pack2_bf16(a1.x, a1.y); fa.u.w = pack2_bf16(a1.z, a1.w);
            fb.u.x = pack2_bf16(b0.x, b0.y); fb.u.y = pack2_bf16(b0.z, b0.w);
            fb.u.z = pack2_bf16(b1v.x, b1v.y); fb.u.w = pack2_bf16(b1v.z, b1v.w);
            acc = __builtin_amdgcn_mfma_f32_16x16x32_bf16(fa.s, fb.s, acc, 0, 0, 0);
        }
        int quad = lane >> 4;
        int bcol = wave * 16 + c;
        #pragma unroll
        for (int i = 0; i < 4; ++i) {
            int hh = mT * 16 + quad * 4 + i;
            sp[((size_t)bcol << 10) + hh] = acc[i] + b1[hh];
        }
    } else {
        // ---- enc -> swizzled bf16 encb: 8 chunk-iterations per thread ----
        // cidx consecutive within a wave -> L = lane (coalesced 1KB stores);
        // 8 independent iterations give 16 float4 loads in flight.
        int base = (blk - 704) * 256 + tid;        // [0, 524288)
        #pragma unroll 8
        for (int j = 0; j < 8; ++j) {
            int cidx = base + j * CONV_STRIDE;     // [0, 4194304) chunk id
            int gr = cidx >> 6;
            int L  = cidx & 63;                    // == lane (wave-aligned)
            int m  = ((gr >> 5) << 4) + (L & 15);
            int k  = ((gr & 31) << 5) + ((L >> 4) << 3);
            const float* src = enc + (size_t)m * 1024 + k;
            float4 v0 = *(const float4*)(src);
            float4 v1 = *(const float4*)(src + 4);
            uint4 o;
            o.x = pack2_bf16(v0.x, v0.y); o.y = pack2_bf16(v0.z, v0.w);
            o.z = pack2_bf16(v1.x, v1.y); o.w = pack2_bf16(v1.z, v1.w);
            *(uint4*)(encb + (size_t)gr * 512 + L * 8) = o;
        }
    }
}

// ------------------------------------------------------------------
// k_energy: C(32768,1024) = encb @ W1e^T, fused tanh/W2/reduce epilogue.
// (round-0 structure, verbatim: best measured configuration.)
// Operands are pre-swizzled in global memory: glds reads are 1KB contiguous
// (base + lane*16B), LDS image is MFMA fragment order (zero conflicts).
#define BM 128
#define BN 128
#define BK 32

__global__ __launch_bounds__(256, 2) void k_energy(const unsigned short* __restrict__ encb,
                                                   const unsigned short* __restrict__ W1e,
                                                   const float* __restrict__ sp,
                                                   const float* __restrict__ W2,
                                                   float* __restrict__ logits) {
    __shared__ unsigned short As[BM * BK];   // 8 KB, regions of 512 shorts
    __shared__ unsigned short Bs[BN * BK];   // 8 KB
    int bid = blockIdx.x;
    int c8  = bid & 7;                // XCD id (round-robin dispatch)
    int jj  = bid >> 3;
    int mT  = c8 * 32 + (jj >> 3);    // same-mT blocks share c8 -> same XCD L2
    int nT  = jj & 7;
    int n0  = nT * BN;
    int m0  = mT * BM;
    int tid  = threadIdx.x;
    int lane = tid & 63, wave = tid >> 6;
    int wm   = (wave >> 1) << 6;
    int wn   = (wave & 1) << 6;

    // staging: wave stages A regions {2w,2w+1} and B regions {2w,2w+1}.
    // Global: swizzled layout, region (RB, KC) at (RB*32+KC)*512 shorts;
    // per-iter advance = KC+1 -> +512 shorts = k0*16.
    int rg0 = wave * 2, rg1 = wave * 2 + 1;
    const unsigned short* gA0 = encb + ((size_t)(mT * 8 + rg0) * 32) * 512 + lane * 8;
    const unsigned short* gA1 = encb + ((size_t)(mT * 8 + rg1) * 32) * 512 + lane * 8;
    const unsigned short* gB0 = W1e  + ((size_t)(nT * 8 + rg0) * 32) * 512 + lane * 8;
    const unsigned short* gB1 = W1e  + ((size_t)(nT * 8 + rg1) * 32) * 512 + lane * 8;
    unsigned short* lA0 = As + rg0 * 512;    // wave-uniform LDS bases
    unsigned short* lA1 = As + rg1 * 512;
    unsigned short* lB0 = Bs + rg0 * 512;
    unsigned short* lB1 = Bs + rg1 * 512;

    f32x4 acc[4][4];
    #pragma unroll
    for (int mi = 0; mi < 4; ++mi)
        #pragma unroll
        for (int ni = 0; ni < 4; ++ni)
            acc[mi][ni] = (f32x4){0.f, 0.f, 0.f, 0.f};

    int ablk = wm >> 4;               // first A region this wave consumes
    int bblk = wn >> 4;
    const unsigned short* afb = As + ablk * 512 + lane * 8;
    const unsigned short* bfb = Bs + bblk * 512 + lane * 8;

    for (int k0 = 0; k0 < H2; k0 += BK) {
        int go = k0 * 16;                      // swizzled-layout offset (shorts)
        __syncthreads();                       // prev iter's LDS reads retired
        gl_lds16(gA0 + go, lA0);
        gl_lds16(gA1 + go, lA1);
        gl_lds16(gB0 + go, lB0);
        gl_lds16(gB1 + go, lB1);
        __syncthreads();                       // vmcnt drain -> tiles visible
        short8 af[4], bf[4];
        #pragma unroll
        for (int i = 0; i < 4; ++i) {
            af[i] = *(const short8*)(afb + i * 512);
            bf[i] = *(const short8*)(bfb + i * 512);
        }
        #pragma unroll
        for (int mi = 0; mi < 4; ++mi)
            #pragma unroll
            for (int ni = 0; ni < 4; ++ni)
                acc[mi][ni] = __builtin_amdgcn_mfma_f32_16x16x32_bf16(af[mi], bf[ni], acc[mi][ni], 0, 0, 0);
    }

    // Epilogue: tanh + W2 dot, quad-shuffle reduce, atomic into logits[b][s]
    int c    = lane & 15;
    int quad = lane >> 4;
    float w2v[4];
    int   hcol[4];
    #pragma unroll
    for (int ni = 0; ni < 4; ++ni) {
        hcol[ni] = n0 + wn + ni * 16 + c;
        w2v[ni]  = W2[hcol[ni]];
    }
    #pragma unroll
    for (int mi = 0; mi < 4; ++mi) {
        #pragma unroll
        for (int i = 0; i < 4; ++i) {
            int m = m0 + wm + mi * 16 + quad * 4 + i;
            int b = m & 63;
            const float* sprow = sp + ((size_t)b << 10);
            float t = 0.f;
            #pragma unroll
            for (int ni = 0; ni < 4; ++ni) {
                float e = acc[mi][ni][i] + sprow[hcol[ni]];
                t = fmaf(fast_tanh(e), w2v[ni], t);
            }
            t += __shfl_xor(t, 1);
            t += __shfl_xor(t, 2);
            t += __shfl_xor(t, 4);
            t += __shfl_xor(t, 8);
            if (c == 0) atomicAdd(logits + (size_t)b * 512 + (m >> 6), t);
        }
    }
}

// ------------------------------------------------------------------
// k_softmax: softmax over s per b.
__global__ __launch_bounds__(256) void k_softmax(const float* __restrict__ logits,
                                                 float* __restrict__ alpha) {
    int b = blockIdx.x;
    int tid = threadIdx.x;
    int lane = tid & 63, wave = tid >> 6;
    float v0 = logits[(size_t)b * 512 + tid];
    float v1 = logits[(size_t)b * 512 + 256 + tid];
    float mx = fmaxf(v0, v1);
    #pragma unroll
    for (int o = 32; o; o >>= 1) mx = fmaxf(mx, __shfl_xor(mx, o));
    __shared__ float redm[4];
    if (lane == 0) redm[wave] = mx;
    __syncthreads();
    mx = fmaxf(fmaxf(redm[0], redm[1]), fmaxf(redm[2], redm[3]));
    float e0 = __expf(v0 - mx), e1 = __expf(v1 - mx);
    float s = e0 + e1;
    #pragma unroll
    for (int o = 32; o; o >>= 1) s += __shfl_xor(s, o);
    __shared__ float reds[4];
    if (lane == 0) reds[wave] = s;
    __syncthreads();
    s = reds[0] + reds[1] + reds[2] + reds[3];
    float inv = 1.0f / s;
    alpha[(size_t)b * 512 + tid]       = e0 * inv;
    alpha[(size_t)b * 512 + 256 + tid] = e1 * inv;
}

// ------------------------------------------------------------------
// k_context: partial ctx over s-chunks, no atomics.
//   grid 2048 = 32 s-chunks x 64 b; part[sc][b][h] aliases dead encb ws.
#define NSC 32
__global__ __launch_bounds__(256) void k_context(const float* __restrict__ enc,
                                                 const float* __restrict__ alpha,
                                                 float* __restrict__ part) {
    int b  = blockIdx.x & 63;
    int sc = blockIdx.x >> 6;            // 0..31
    int h  = threadIdx.x << 2;
    float4 acc = make_float4(0.f, 0.f, 0.f, 0.f);
    int sbase = sc * 16;
    #pragma unroll
    for (int si = 0; si < 16; ++si) {
        int s = sbase + si;
        float a = alpha[(size_t)b * 512 + s];
        float4 e = *(const float4*)(enc + (((size_t)s * 64 + b) << 10) + h);
        acc.x = fmaf(a, e.x, acc.x);
        acc.y = fmaf(a, e.y, acc.y);
        acc.z = fmaf(a, e.z, acc.z);
        acc.w = fmaf(a, e.w, acc.w);
    }
    *(float4*)(part + (((size_t)sc * 64 + b) << 10) + h) = acc;
}

// k_reduce: ctx[b][h] = sum_sc part[sc][b][h].  64 blocks x 256 thr x float4.
__global__ __launch_bounds__(256) void k_reduce(const float* __restrict__ part,
                                                float* __restrict__ ctx) {
    int b = blockIdx.x;
    int h = threadIdx.x << 2;
    float4 acc = make_float4(0.f, 0.f, 0.f, 0.f);
    #pragma unroll
    for (int sc = 0; sc < NSC; ++sc) {
        float4 p = *(const float4*)(part + (((size_t)sc * 64 + b) << 10) + h);
        acc.x += p.x; acc.y += p.y; acc.z += p.z; acc.w += p.w;
    }
    *(float4*)(ctx + ((size_t)b << 10) + h) = acc;
}

// ------------------------------------------------------------------
extern "C" void kernel_launch(void* const* d_in, const int* in_sizes, int n_in,
                              void* d_out, int out_size, void* d_ws, size_t ws_size,
                              hipStream_t stream) {
    const float* state = (const float*)d_in[0];   // (2, 64, 1024)
    const float* enc   = (const float*)d_in[1];   // (512, 64, 1024)
    const float* W1    = (const float*)d_in[2];   // (1024, 3072)
    const float* b1    = (const float*)d_in[3];   // (1024,)
    const float* W2    = (const float*)d_in[4];   // (1, 1024)
    // d_in[5] = b2: dropped — softmax is shift-invariant.

    float* ctx   = (float*)d_out;                 // (1,64,1024) = 65536 fp32
    float* alpha = (float*)d_out + 65536;         // (64,1,512)  = 32768 fp32

    char* ws = (char*)d_ws;
    unsigned short* W1e    = (unsigned short*)(ws);             // 2 MB bf16 swizzled
    float*          sp     = (float*)(ws + 2097152);            // 256 KB [b][h]
    float*          logits = (float*)(ws + 2097152 + 262144);   // 128 KB [b][s]
    unsigned short* encb   = (unsigned short*)(ws + 2097152 + 262144 + 131072); // 64 MB
    float*          part   = (float*)encb;        // aliases encb (dead after k_energy)

    k_setup<<<704 + CONV_BLKS, 256, 0, stream>>>(W1, b1, state, enc, W1e, encb,
                                                 logits, sp);
    k_energy<<<M_TOTAL / BM * (H2 / BN), 256, 0, stream>>>(encb, W1e, sp, W2, logits);
    k_softmax<<<64, 256, 0, stream>>>(logits, alpha);
    k_context<<<NSC * 64, 256, 0, stream>>>(enc, alpha, part);
    k_reduce<<<64, 256, 0, stream>>>(part, ctx);
}

// Round 6
// 344.953 us; speedup vs baseline: 1.6938x; 1.1047x over previous
//
#include <hip/hip_runtime.h>
#include <hip/hip_bf16.h>
#include <stdint.h>

// Problem constants
#define H2      1024
#define SEQ     512
#define BATCH   64
#define M_TOTAL (SEQ * BATCH)   // 32768 rows, row m = s*64 + b (enc layout (S,B,H2))

typedef __attribute__((ext_vector_type(8))) short short8;  // 8 bf16 (4 VGPRs)
typedef __attribute__((ext_vector_type(4))) float f32x4;   // mfma acc

__device__ __forceinline__ unsigned pack2_bf16(float lo, float hi) {
    union { __hip_bfloat162 h; unsigned u; } v;
    v.h = __float22bfloat162_rn(make_float2(lo, hi));
    return v.u;
}

__device__ __forceinline__ float fast_tanh(float x) {
    float e = __expf(2.0f * x);
    return __fdividef(e - 1.0f, e + 1.0f);
}

// Async global->LDS, 16B per lane; LDS dest = wave-uniform base + lane*16B.
__device__ __forceinline__ void gl_lds16(const unsigned short* g, unsigned short* l) {
    __builtin_amdgcn_global_load_lds(
        (const __attribute__((address_space(1))) unsigned int*)g,
        (__attribute__((address_space(3))) unsigned int*)l, 16, 0, 0);
}

// Swizzled operand layout (MFMA-fragment-major), bf16:
//   region gr = RB*32 + KC  (RB = row>>4, KC = k>>5), 512 shorts each.
//   chunk L in [0,64): 8 shorts = (row = RB*16 + (L&15), k = KC*32 + (L>>4)*8).
//
// enc conversion uses an LDS bounce so BOTH global phases are wave-contiguous
// 1KB bursts (the straight-from-global version scatters each load over 16
// rows x 16B -> ~32 transactions/instr -> TA-serialization-bound at 1.7 TB/s).

// ------------------------------------------------------------------
// k_setup: fused prep. Block ranges:
//   [0,512)      : W1 enc-slice -> bf16 W1e swizzled
//   [512,640)    : zero logits (32768)
//   [640,704)    : state projection sp[b][h] = sum_k st*W1 + b1 (both layers)
//   [704,2752)   : enc fp32 -> bf16 swizzled encb via LDS-bounce transpose
__global__ __launch_bounds__(256) void k_setup(const float* __restrict__ W1,
                                               const float* __restrict__ b1,
                                               const float* __restrict__ state,
                                               const float* __restrict__ enc,
                                               unsigned short* __restrict__ W1e,
                                               unsigned short* __restrict__ encb,
                                               float* __restrict__ logits,
                                               float* __restrict__ sp) {
    __shared__ unsigned short T[16 * 1024];    // 32 KB bounce buffer (conv blocks)
    int blk = blockIdx.x, tid = threadIdx.x;
    int lane = tid & 63;
    if (blk < 512) {
        // ---- W1e prep: wave w -> region blk*4+w, chunk L = lane ----
        int gr = blk * 4 + (tid >> 6);
        int h  = ((gr >> 5) << 4) + (lane & 15);
        int k  = ((gr & 31) << 5) + ((lane >> 4) << 3);
        const float* src = W1 + (size_t)h * 3072 + 2048 + k;
        float4 v0 = *(const float4*)(src);
        float4 v1 = *(const float4*)(src + 4);
        uint4 o;
        o.x = pack2_bf16(v0.x, v0.y); o.y = pack2_bf16(v0.z, v0.w);
        o.z = pack2_bf16(v1.x, v1.y); o.w = pack2_bf16(v1.z, v1.w);
        *(uint4*)(W1e + (size_t)gr * 512 + lane * 8) = o;   // 1KB burst per wave
    } else if (blk < 640) {
        logits[(blk - 512) * 256 + tid] = 0.f;
    } else if (blk < 704) {
        // ---- state projection: mT = blk-640 (16 h-rows), all 64 b, K=2048 ----
        int mT   = blk - 640;
        int wave = tid >> 6;                // b-tile 0..3
        int c    = lane & 15;
        int kq   = (lane >> 4) << 3;
        int h    = mT * 16 + c;
        int b    = wave * 16 + c;
        const float* ap = W1 + (size_t)h * 3072 + kq;   // state cols [0,2048)
        f32x4 acc = {0.f, 0.f, 0.f, 0.f};
        #pragma unroll 4
        for (int k0 = 0; k0 < 2048; k0 += 32) {
            int k = k0 + kq;
            float4 a0 = *(const float4*)(ap + k0);
            float4 a1 = *(const float4*)(ap + k0 + 4);
            int l = k >> 10, j = k & 1023;
            const float* bp = state + (((size_t)l * 64 + b) << 10) + j;
            float4 b0 = *(const float4*)bp;
            float4 b1v = *(const float4*)(bp + 4);
            union { short8 s; uint4 u; } fa, fb;
            fa.u.x = pack2_bf16(a0.x, a0.y); fa.u.y = pack2_bf16(a0.z, a0.w);
            fa.u.z = pack2_bf16(a1.x, a1.y); fa.u.w = pack2_bf16(a1.z, a1.w);
            fb.u.x = pack2_bf16(b0.x, b0.y); fb.u.y = pack2_bf16(b0.z, b0.w);
            fb.u.z = pack2_bf16(b1v.x, b1v.y); fb.u.w = pack2_bf16(b1v.z, b1v.w);
            acc = __builtin_amdgcn_mfma_f32_16x16x32_bf16(fa.s, fb.s, acc, 0, 0, 0);
        }
        int quad = lane >> 4;
        int bcol = wave * 16 + c;
        #pragma unroll
        for (int i = 0; i < 4; ++i) {
            int hh = mT * 16 + quad * 4 + i;
            sp[((size_t)bcol << 10) + hh] = acc[i] + b1[hh];
        }
    } else {
        // ---- enc -> encb LDS-bounce transpose. One RB stripe per block:
        // 16 consecutive rows = 64 KB CONTIGUOUS in enc; 32 KB contiguous out.
        int RB = blk - 704;                               // 0..2047
        const float*    src = enc  + (size_t)RB * 16384;  // 16*1024 floats
        unsigned short* dst = encb + (size_t)RB * 16384;  // 32 regions * 512 sh

        // Phase 1: streaming read. Pass p reads row p: 256 thr x float4 = 4KB;
        // each wave-load is 1KB lane-contiguous. Convert, write 8B to LDS at
        // logical (row-major [16][1024] shorts) addr with XOR swizzle
        // byte ^= (row&7)<<4 (bijective per 128B line; phase-2 conflict-free).
        float4 v[16];
        #pragma unroll
        for (int p = 0; p < 16; ++p)
            v[p] = *(const float4*)(src + p * 1024 + (tid << 2));
        #pragma unroll
        for (int p = 0; p < 16; ++p) {
            uint2 o;
            o.x = pack2_bf16(v[p].x, v[p].y);
            o.y = pack2_bf16(v[p].z, v[p].w);
            int byte = (p * 2048 + (tid << 3)) ^ ((p & 7) << 4);
            *(uint2*)((char*)T + byte) = o;
        }
        __syncthreads();

        // Phase 2: fragment-order readout. Chunk c = (KC = c>>6, L = c&63):
        // row = L&15, k = KC*32 + (L>>4)*8. LDS read 16B (2 lanes/bank-window
        // after XOR => free); store c*16B -> wave-contiguous 1KB bursts.
        #pragma unroll
        for (int q = 0; q < 8; ++q) {
            int cchunk = q * 256 + tid;                    // [0,2048)
            int KC  = cchunk >> 6;
            int L   = cchunk & 63;
            int row = L & 15;
            int kb  = KC * 64 + ((L >> 4) << 4);           // byte off of k*2
            int byte = (row * 2048 + kb) ^ ((row & 7) << 4);
            uint4 d = *(const uint4*)((const char*)T + byte);
            *(uint4*)(dst + (size_t)cchunk * 8) = d;
        }
    }
}

// ------------------------------------------------------------------
// k_energy: C(32768,1024) = encb @ W1e^T, fused tanh/W2/reduce epilogue.
// (round-0 structure, verbatim: best measured configuration.)
#define BM 128
#define BN 128
#define BK 32

__global__ __launch_bounds__(256, 2) void k_energy(const unsigned short* __restrict__ encb,
                                                   const unsigned short* __restrict__ W1e,
                                                   const float* __restrict__ sp,
                                                   const float* __restrict__ W2,
                                                   float* __restrict__ logits) {
    __shared__ unsigned short As[BM * BK];   // 8 KB, regions of 512 shorts
    __shared__ unsigned short Bs[BN * BK];   // 8 KB
    int bid = blockIdx.x;
    int c8  = bid & 7;                // XCD id (round-robin dispatch)
    int jj  = bid >> 3;
    int mT  = c8 * 32 + (jj >> 3);    // same-mT blocks share c8 -> same XCD L2
    int nT  = jj & 7;
    int n0  = nT * BN;
    int m0  = mT * BM;
    int tid  = threadIdx.x;
    int lane = tid & 63, wave = tid >> 6;
    int wm   = (wave >> 1) << 6;
    int wn   = (wave & 1) << 6;

    int rg0 = wave * 2, rg1 = wave * 2 + 1;
    const unsigned short* gA0 = encb + ((size_t)(mT * 8 + rg0) * 32) * 512 + lane * 8;
    const unsigned short* gA1 = encb + ((size_t)(mT * 8 + rg1) * 32) * 512 + lane * 8;
    const unsigned short* gB0 = W1e  + ((size_t)(nT * 8 + rg0) * 32) * 512 + lane * 8;
    const unsigned short* gB1 = W1e  + ((size_t)(nT * 8 + rg1) * 32) * 512 + lane * 8;
    unsigned short* lA0 = As + rg0 * 512;    // wave-uniform LDS bases
    unsigned short* lA1 = As + rg1 * 512;
    unsigned short* lB0 = Bs + rg0 * 512;
    unsigned short* lB1 = Bs + rg1 * 512;

    f32x4 acc[4][4];
    #pragma unroll
    for (int mi = 0; mi < 4; ++mi)
        #pragma unroll
        for (int ni = 0; ni < 4; ++ni)
            acc[mi][ni] = (f32x4){0.f, 0.f, 0.f, 0.f};

    int ablk = wm >> 4;               // first A region this wave consumes
    int bblk = wn >> 4;
    const unsigned short* afb = As + ablk * 512 + lane * 8;
    const unsigned short* bfb = Bs + bblk * 512 + lane * 8;

    for (int k0 = 0; k0 < H2; k0 += BK) {
        int go = k0 * 16;                      // swizzled-layout offset (shorts)
        __syncthreads();                       // prev iter's LDS reads retired
        gl_lds16(gA0 + go, lA0);
        gl_lds16(gA1 + go, lA1);
        gl_lds16(gB0 + go, lB0);
        gl_lds16(gB1 + go, lB1);
        __syncthreads();                       // vmcnt drain -> tiles visible
        short8 af[4], bf[4];
        #pragma unroll
        for (int i = 0; i < 4; ++i) {
            af[i] = *(const short8*)(afb + i * 512);
            bf[i] = *(const short8*)(bfb + i * 512);
        }
        #pragma unroll
        for (int mi = 0; mi < 4; ++mi)
            #pragma unroll
            for (int ni = 0; ni < 4; ++ni)
                acc[mi][ni] = __builtin_amdgcn_mfma_f32_16x16x32_bf16(af[mi], bf[ni], acc[mi][ni], 0, 0, 0);
    }

    // Epilogue: tanh + W2 dot, quad-shuffle reduce, atomic into logits[b][s]
    int c    = lane & 15;
    int quad = lane >> 4;
    float w2v[4];
    int   hcol[4];
    #pragma unroll
    for (int ni = 0; ni < 4; ++ni) {
        hcol[ni] = n0 + wn + ni * 16 + c;
        w2v[ni]  = W2[hcol[ni]];
    }
    #pragma unroll
    for (int mi = 0; mi < 4; ++mi) {
        #pragma unroll
        for (int i = 0; i < 4; ++i) {
            int m = m0 + wm + mi * 16 + quad * 4 + i;
            int b = m & 63;
            const float* sprow = sp + ((size_t)b << 10);
            float t = 0.f;
            #pragma unroll
            for (int ni = 0; ni < 4; ++ni) {
                float e = acc[mi][ni][i] + sprow[hcol[ni]];
                t = fmaf(fast_tanh(e), w2v[ni], t);
            }
            t += __shfl_xor(t, 1);
            t += __shfl_xor(t, 2);
            t += __shfl_xor(t, 4);
            t += __shfl_xor(t, 8);
            if (c == 0) atomicAdd(logits + (size_t)b * 512 + (m >> 6), t);
        }
    }
}

// ------------------------------------------------------------------
// k_softmax: softmax over s per b.
__global__ __launch_bounds__(256) void k_softmax(const float* __restrict__ logits,
                                                 float* __restrict__ alpha) {
    int b = blockIdx.x;
    int tid = threadIdx.x;
    int lane = tid & 63, wave = tid >> 6;
    float v0 = logits[(size_t)b * 512 + tid];
    float v1 = logits[(size_t)b * 512 + 256 + tid];
    float mx = fmaxf(v0, v1);
    #pragma unroll
    for (int o = 32; o; o >>= 1) mx = fmaxf(mx, __shfl_xor(mx, o));
    __shared__ float redm[4];
    if (lane == 0) redm[wave] = mx;
    __syncthreads();
    mx = fmaxf(fmaxf(redm[0], redm[1]), fmaxf(redm[2], redm[3]));
    float e0 = __expf(v0 - mx), e1 = __expf(v1 - mx);
    float s = e0 + e1;
    #pragma unroll
    for (int o = 32; o; o >>= 1) s += __shfl_xor(s, o);
    __shared__ float reds[4];
    if (lane == 0) reds[wave] = s;
    __syncthreads();
    s = reds[0] + reds[1] + reds[2] + reds[3];
    float inv = 1.0f / s;
    alpha[(size_t)b * 512 + tid]       = e0 * inv;
    alpha[(size_t)b * 512 + 256 + tid] = e1 * inv;
}

// ------------------------------------------------------------------
// k_context: partial ctx over s-chunks, no atomics.
//   grid 2048 = 32 s-chunks x 64 b; part[sc][b][h] aliases dead encb ws.
#define NSC 32
__global__ __launch_bounds__(256) void k_context(const float* __restrict__ enc,
                                                 const float* __restrict__ alpha,
                                                 float* __restrict__ part) {
    int b  = blockIdx.x & 63;
    int sc = blockIdx.x >> 6;            // 0..31
    int h  = threadIdx.x << 2;
    float4 acc = make_float4(0.f, 0.f, 0.f, 0.f);
    int sbase = sc * 16;
    #pragma unroll
    for (int si = 0; si < 16; ++si) {
        int s = sbase + si;
        float a = alpha[(size_t)b * 512 + s];
        float4 e = *(const float4*)(enc + (((size_t)s * 64 + b) << 10) + h);
        acc.x = fmaf(a, e.x, acc.x);
        acc.y = fmaf(a, e.y, acc.y);
        acc.z = fmaf(a, e.z, acc.z);
        acc.w = fmaf(a, e.w, acc.w);
    }
    *(float4*)(part + (((size_t)sc * 64 + b) << 10) + h) = acc;
}

// k_reduce: ctx[b][h] = sum_sc part[sc][b][h].  64 blocks x 256 thr x float4.
__global__ __launch_bounds__(256) void k_reduce(const float* __restrict__ part,
                                                float* __restrict__ ctx) {
    int b = blockIdx.x;
    int h = threadIdx.x << 2;
    float4 acc = make_float4(0.f, 0.f, 0.f, 0.f);
    #pragma unroll
    for (int sc = 0; sc < NSC; ++sc) {
        float4 p = *(const float4*)(part + (((size_t)sc * 64 + b) << 10) + h);
        acc.x += p.x; acc.y += p.y; acc.z += p.z; acc.w += p.w;
    }
    *(float4*)(ctx + ((size_t)b << 10) + h) = acc;
}

// ------------------------------------------------------------------
extern "C" void kernel_launch(void* const* d_in, const int* in_sizes, int n_in,
                              void* d_out, int out_size, void* d_ws, size_t ws_size,
                              hipStream_t stream) {
    const float* state = (const float*)d_in[0];   // (2, 64, 1024)
    const float* enc   = (const float*)d_in[1];   // (512, 64, 1024)
    const float* W1    = (const float*)d_in[2];   // (1024, 3072)
    const float* b1    = (const float*)d_in[3];   // (1024,)
    const float* W2    = (const float*)d_in[4];   // (1, 1024)
    // d_in[5] = b2: dropped — softmax is shift-invariant.

    float* ctx   = (float*)d_out;                 // (1,64,1024) = 65536 fp32
    float* alpha = (float*)d_out + 65536;         // (64,1,512)  = 32768 fp32

    char* ws = (char*)d_ws;
    unsigned short* W1e    = (unsigned short*)(ws);             // 2 MB bf16 swizzled
    float*          sp     = (float*)(ws + 2097152);            // 256 KB [b][h]
    float*          logits = (float*)(ws + 2097152 + 262144);   // 128 KB [b][s]
    unsigned short* encb   = (unsigned short*)(ws + 2097152 + 262144 + 131072); // 64 MB
    float*          part   = (float*)encb;        // aliases encb (dead after k_energy)

    k_setup<<<704 + 2048, 256, 0, stream>>>(W1, b1, state, enc, W1e, encb,
                                            logits, sp);
    k_energy<<<M_TOTAL / BM * (H2 / BN), 256, 0, stream>>>(encb, W1e, sp, W2, logits);
    k_softmax<<<64, 256, 0, stream>>>(logits, alpha);
    k_context<<<NSC * 64, 256, 0, stream>>>(enc, alpha, part);
    k_reduce<<<64, 256, 0, stream>>>(part, ctx);
}